// Round 15
// baseline (264.290 us; speedup 1.0000x reference)
//
#include <hip/hip_runtime.h>
#include <hip/hip_bf16.h>
#include <hip/hip_fp16.h>

typedef unsigned int u32;
typedef unsigned short u16;

__device__ __forceinline__ float lrelu(float v) {
    return v > 0.f ? v : 0.2f * v;
}

// load quad q (4 halves = 8B) of a 16-half planar row, convert to float4
__device__ __forceinline__ float4 ldq_h16(const u16* __restrict__ row, int q) {
    uint2 u = ((const uint2*)row)[q];
    __half2 a = *(__half2*)&u.x;
    __half2 b = *(__half2*)&u.y;
    float2 fa = __half22float2(a);
    float2 fb = __half22float2(b);
    return make_float4(fa.x, fa.y, fb.x, fb.y);
}

__device__ __forceinline__ u32 pack2h(float x, float y) {
    __half2 h = __float22half2_rn(make_float2(x, y));
    return *(u32*)&h;
}

#define PCHUNK 4096
#define NW 256

// ---------------- partition (standalone, full occupancy) -------------------
__global__ __launch_bounds__(256) void partition_kernel(
    const int* __restrict__ srcI, const int* __restrict__ dstI,
    u32* __restrict__ pairs, u32* __restrict__ bcur,
    int E, int wsz, int cap)
{
    __shared__ u32 lcount[NW];
    __shared__ u32 lbase[NW];
    int t = threadIdx.x;
    int chunk = blockIdx.x * PCHUNK;
    lcount[t] = 0;
    __syncthreads();
    u32 pk[16]; int wv[16]; u32 rk[16]; bool val[16];
#pragma unroll
    for (int g = 0; g < 4; g++) {
        int i0 = chunk + g * 1024 + 4 * t;
        int4 s4, d4;
        bool v4 = (i0 + 3) < E;
        if (v4) {
            s4 = *(const int4*)&srcI[i0];
            d4 = *(const int4*)&dstI[i0];
        }
        int sv[4] = {s4.x, s4.y, s4.z, s4.w};
        int dv[4] = {d4.x, d4.y, d4.z, d4.w};
#pragma unroll
        for (int j = 0; j < 4; j++) {
            int k = g * 4 + j;
            int i = i0 + j;
            val[k] = i < E;
            if (val[k]) {
                u32 s, d;
                if (v4) { s = (u32)sv[j]; d = (u32)dv[j]; }
                else    { s = (u32)srcI[i]; d = (u32)dstI[i]; }
                wv[k] = d / (u32)wsz;
                u32 dloc = d - (u32)wv[k] * (u32)wsz;
                pk[k] = (dloc << 17) | s;
                rk[k] = atomicAdd(&lcount[wv[k]], 1u);
            }
        }
    }
    __syncthreads();
    if (lcount[t] > 0)
        lbase[t] = atomicAdd(&bcur[t], lcount[t]);
    __syncthreads();
#pragma unroll
    for (int k = 0; k < 16; k++) {
        if (val[k]) {
            u32 pos = lbase[wv[k]] + rk[k];
            if (pos < (u32)cap)   // overflow guard (P ~ 0, 39 sigma)
                pairs[(size_t)wv[k] * cap + pos] = pk[k];
        }
    }
}

// Shared-memory overlays for the csr ∥ gemm1 fat kernel.
struct GSm { float xs[64][132]; float Wl[128][32]; float asv[32], adv[32]; };
struct CSm { u32 dw[512], cw[512], ts[256], hb[512]; };

// ---------------- FAT: csr (blocks [0,NW)) ∥ gemm1 (rest) ------------------
// gemm1 now writes PLANAR fp16: hA = ch[0,16), hB = ch[16,32) (3.2MB each,
// per-plane L2-resident for l1g2's two-pass gather).
__global__ __launch_bounds__(256) void g1c_kernel(
    const float* __restrict__ x, const float* __restrict__ W,
    const float* __restrict__ a_src, const float* __restrict__ a_dst,
    u16* __restrict__ hA, u16* __restrict__ hB,
    float* __restrict__ as_, float* __restrict__ ad_,
    const u32* __restrict__ pairs, const u32* __restrict__ bcur,
    u32* __restrict__ rowS, u32* __restrict__ deg, int* __restrict__ srcS,
    u32* __restrict__ perm,
    int n, int wsz, int cap)
{
    __shared__ __align__(16) char smraw[sizeof(GSm)];
    int t = threadIdx.x;

    if ((int)blockIdx.x < NW) {
        // ---- csr body (R12-verbatim, arrays via overlay) ----
        CSm& s = *reinterpret_cast<CSm*>(smraw);
        int grp = blockIdx.x;
        int wlo = grp * wsz;
        int wnodes = n - wlo; if (wnodes < 0) wnodes = 0; if (wnodes > wsz) wnodes = wsz;
        u32 cnt = bcur[grp]; if (cnt > (u32)cap) cnt = (u32)cap;
        size_t base = (size_t)grp * cap;

        {
            int wlo_t = t * wsz;
            int wn_t = n - wlo_t; if (wn_t < 0) wn_t = 0; if (wn_t > wsz) wn_t = wsz;
            u32 c_t = bcur[t]; if (c_t > (u32)cap) c_t = (u32)cap;
            s.ts[t] = c_t + (u32)wn_t;
            __syncthreads();
            for (int o = 1; o < NW; o <<= 1) {
                u32 y = (t >= o) ? s.ts[t - o] : 0u;
                __syncthreads();
                s.ts[t] += y;
                __syncthreads();
            }
        }
        u32 wb = s.ts[grp] - (cnt + (u32)wnodes);
        __syncthreads();

        s.dw[t] = 0; s.dw[t + 256] = 0;
        s.hb[t] = 0; s.hb[t + 256] = 0;
        __syncthreads();
        for (u32 i = t; i < cnt; i += 256)
            atomicAdd(&s.dw[pairs[base + i] >> 17], 1u);
        __syncthreads();

        int i0 = 2 * t, i1 = 2 * t + 1;
        u32 e0 = (i0 < wnodes) ? s.dw[i0] + 1u : 0u;
        u32 e1 = (i1 < wnodes) ? s.dw[i1] + 1u : 0u;
        s.ts[t] = e0 + e1;
        __syncthreads();
        for (int o = 1; o < 256; o <<= 1) {
            u32 y = (t >= o) ? s.ts[t - o] : 0u;
            __syncthreads();
            s.ts[t] += y;
            __syncthreads();
        }
        u32 off = wb + s.ts[t] - (e0 + e1);
        if (i0 < wnodes) {
            u32 dgi = s.dw[i0];
            s.cw[i0] = off;
            rowS[wlo + i0] = off;
            deg[wlo + i0] = dgi;
            srcS[off + dgi] = wlo + i0;      // self-loop at last slot
        }
        u32 off1 = off + e0;
        if (i1 < wnodes) {
            u32 dgi = s.dw[i1];
            s.cw[i1] = off1;
            rowS[wlo + i1] = off1;
            deg[wlo + i1] = dgi;
            srcS[off1 + dgi] = wlo + i1;
        }
        __syncthreads();

        // degree counting-sort -> perm (ascending degree within window)
        for (int i = t; i < wnodes; i += 256)
            atomicAdd(&s.hb[s.dw[i] < 511u ? s.dw[i] : 511u], 1u);
        __syncthreads();
        {
            u32 h0 = s.hb[2 * t], h1 = s.hb[2 * t + 1];
            s.ts[t] = h0 + h1;
            __syncthreads();
            for (int o = 1; o < 256; o <<= 1) {
                u32 y = (t >= o) ? s.ts[t - o] : 0u;
                __syncthreads();
                s.ts[t] += y;
                __syncthreads();
            }
            u32 b0 = s.ts[t] - (h0 + h1);
            s.hb[2 * t] = b0;
            s.hb[2 * t + 1] = b0 + h0;
        }
        __syncthreads();
        for (int i = t; i < wnodes; i += 256) {
            u32 dg = s.dw[i] < 511u ? s.dw[i] : 511u;
            u32 pos = atomicAdd(&s.hb[dg], 1u);
            perm[wlo + pos] = (u32)(wlo + i);
        }
        for (int i = wnodes + t; i < wsz; i += 256)
            perm[wlo + i] = 0x7fffffffu;      // pad sentinel
        __syncthreads();

        // scatter (slab L2-hot from hist pass)
        for (u32 i = t; i < cnt; i += 256) {
            u32 pr = pairs[base + i];
            u32 pos = atomicAdd(&s.cw[pr >> 17], 1u);
            srcS[pos] = (int)(pr & 0x1FFFFu);
        }
        return;
    }

    // ---- gemm1 body (R8-exact loop): planar fp16 out + as_/ad_ dots ----
    GSm& s = *reinterpret_cast<GSm*>(smraw);
    int rb = (blockIdx.x - NW) * 64;

    for (int i = t; i < 4096; i += 256) s.Wl[i >> 5][i & 31] = W[i];
    if (t < 32) { s.asv[t] = a_src[t]; s.adv[t] = a_dst[t]; }
    for (int i = t; i < 2048; i += 256) {
        int row = i >> 5, seg = i & 31;
        float4 v = make_float4(0.f, 0.f, 0.f, 0.f);
        if (rb + row < n)
            v = ((const float4*)(x + (size_t)(rb + row) * 128))[seg];
        int c = seg * 4;
        s.xs[row][c + 0] = v.x; s.xs[row][c + 1] = v.y;
        s.xs[row][c + 2] = v.z; s.xs[row][c + 3] = v.w;
    }
    __syncthreads();

    int tr = t >> 3;
    int tc = t & 7;
    float acc[2][4];
#pragma unroll
    for (int i = 0; i < 2; i++)
#pragma unroll
        for (int j = 0; j < 4; j++) acc[i][j] = 0.f;

#pragma unroll 4
    for (int k = 0; k < 128; k++) {
        float x0 = s.xs[tr][k];
        float x1 = s.xs[tr + 32][k];
        float4 wv = *(const float4*)&s.Wl[k][tc * 4];
        acc[0][0] += x0 * wv.x; acc[0][1] += x0 * wv.y;
        acc[0][2] += x0 * wv.z; acc[0][3] += x0 * wv.w;
        acc[1][0] += x1 * wv.x; acc[1][1] += x1 * wv.y;
        acc[1][2] += x1 * wv.z; acc[1][3] += x1 * wv.w;
    }

#pragma unroll
    for (int i = 0; i < 2; i++) {
        int r = rb + tr + i * 32;
        if (r < n) {
            uint2 p;
            p.x = pack2h(acc[i][0], acc[i][1]);
            p.y = pack2h(acc[i][2], acc[i][3]);
            u16* plane = (tc < 4) ? hA : hB;
            *(uint2*)&plane[(size_t)r * 16 + (tc & 3) * 4] = p;
        }
        float ps = 0.f, pd = 0.f;
#pragma unroll
        for (int j = 0; j < 4; j++) {
            int c = tc * 4 + j;
            ps += acc[i][j] * s.asv[c];
            pd += acc[i][j] * s.adv[c];
        }
        for (int m = 1; m < 8; m <<= 1) {
            ps += __shfl_xor(ps, m, 64);
            pd += __shfl_xor(pd, m, 64);
        }
        if (tc == 0 && r < n) { as_[r] = ps; ad_[r] = pd; }
    }
}

// ------------ layer-1 + GEMM2 fused (two-pass planar gather) ---------------
// Group = 4 edges x 4 quads (e4/q4). Pass A gathers plane hA (3.2MB, L2-
// resident), pass B plane hB. Weights identical both passes; wsum in A only.
// Full-tile/tail split kept. NO EARLY RETURNS (barriers).
__global__ __launch_bounds__(256) void l1g2_kernel(
    const u32* __restrict__ rowS, const u32* __restrict__ deg,
    const int* __restrict__ srcS, const u32* __restrict__ perm,
    const float* __restrict__ as_, const float* __restrict__ ad_,
    const u16* __restrict__ hA, const u16* __restrict__ hB,
    const float* __restrict__ b1,
    const float* __restrict__ Wm, const float* __restrict__ Wl_,
    const float* __restrict__ ams, const float* __restrict__ amd,
    const float* __restrict__ alsb, const float* __restrict__ ald,
    u16* __restrict__ hmu, u16* __restrict__ hls, float2* __restrict__ attn2,
    float* __restrict__ amud, float* __restrict__ alsd,
    int n, int ntot)
{
    __shared__ float hs[16][36];
    __shared__ float Wms[32][16], Wls[32][16];
    __shared__ float amsv[16], amdv[16], alsv[16], aldv[16];
    __shared__ int dsl[16];
    int t = threadIdx.x;

    for (int i = t; i < 512; i += 256) {
        Wms[i >> 4][i & 15] = Wm[i];
        Wls[i >> 4][i & 15] = Wl_[i];
    }
    if (t < 16) {
        amsv[t] = ams[t]; amdv[t] = amd[t];
        alsv[t] = alsb[t]; aldv[t] = ald[t];
    }

    int gid = blockIdx.x * 16 + (t >> 4);
    int d = (gid < ntot) ? (int)perm[gid] : 0x7fffffff;
    bool live = (u32)d < (u32)n;
    int l  = t & 15;           // lane in group
    int e4 = l >> 2;           // edge slot (4 in flight)
    int q4 = l & 3;            // quad of the 16-ch half row
    int gb = (t & 63) & 48;    // group base lane within wave

    int beg = 0, end = 0;
    float adv = 0.f;
    if (live) {
        beg = (int)rowS[d];
        end = beg + (int)deg[d] + 1;
        adv = ad_[d];
    }
    int full_end = beg + ((end - beg) & ~15);

    float wsum = 0.f;
    float4 accA = make_float4(0.f, 0.f, 0.f, 0.f);
    float4 accB = make_float4(0.f, 0.f, 0.f, 0.f);

    // ---- pass A: plane hA, accumulate wsum ----
    int tb = beg;
    for (; tb < full_end; tb += 16) {
        int s = srcS[tb + l];
        float p = __expf(fminf(lrelu(as_[s] + adv), 60.f));
#pragma unroll
        for (int jj = 0; jj < 16; jj += 4) {
            int idx = jj + e4;
            int sj  = __shfl(s, gb + idx, 64);
            float w = __shfl(p, gb + idx, 64);
            wsum += w;
            float4 hv = ldq_h16(hA + (size_t)sj * 16, q4);
            accA.x += w * hv.x; accA.y += w * hv.y;
            accA.z += w * hv.z; accA.w += w * hv.w;
        }
    }
    if (tb < end) {
        int j = tb + l;
        bool valid = j < end;
        int s = valid ? srcS[j] : 0;
        float p = valid ? __expf(fminf(lrelu(as_[s] + adv), 60.f)) : 0.f;
        int cnt = end - tb;
        for (int jj = 0; jj < cnt; jj += 4) {
            int idx = jj + e4;
            int sj  = __shfl(s, gb + idx, 64);
            float w = __shfl(p, gb + idx, 64);
            if (idx >= cnt) w = 0.f;
            wsum += w;
            float4 hv = ldq_h16(hA + (size_t)sj * 16, q4);
            accA.x += w * hv.x; accA.y += w * hv.y;
            accA.z += w * hv.z; accA.w += w * hv.w;
        }
    }
    // ---- pass B: plane hB (weights recomputed; as_ is L2-hot) ----
    tb = beg;
    for (; tb < full_end; tb += 16) {
        int s = srcS[tb + l];
        float p = __expf(fminf(lrelu(as_[s] + adv), 60.f));
#pragma unroll
        for (int jj = 0; jj < 16; jj += 4) {
            int idx = jj + e4;
            int sj  = __shfl(s, gb + idx, 64);
            float w = __shfl(p, gb + idx, 64);
            float4 hv = ldq_h16(hB + (size_t)sj * 16, q4);
            accB.x += w * hv.x; accB.y += w * hv.y;
            accB.z += w * hv.z; accB.w += w * hv.w;
        }
    }
    if (tb < end) {
        int j = tb + l;
        bool valid = j < end;
        int s = valid ? srcS[j] : 0;
        float p = valid ? __expf(fminf(lrelu(as_[s] + adv), 60.f)) : 0.f;
        int cnt = end - tb;
        for (int jj = 0; jj < cnt; jj += 4) {
            int idx = jj + e4;
            int sj  = __shfl(s, gb + idx, 64);
            float w = __shfl(p, gb + idx, 64);
            if (idx >= cnt) w = 0.f;
            float4 hv = ldq_h16(hB + (size_t)sj * 16, q4);
            accB.x += w * hv.x; accB.y += w * hv.y;
            accB.z += w * hv.z; accB.w += w * hv.w;
        }
    }

    // fold over e4 (lane bits 2,3)
#pragma unroll
    for (int o = 4; o <= 8; o <<= 1) {
        wsum  += __shfl_xor(wsum, o, 64);
        accA.x += __shfl_xor(accA.x, o, 64);
        accA.y += __shfl_xor(accA.y, o, 64);
        accA.z += __shfl_xor(accA.z, o, 64);
        accA.w += __shfl_xor(accA.w, o, 64);
        accB.x += __shfl_xor(accB.x, o, 64);
        accB.y += __shfl_xor(accB.y, o, 64);
        accB.z += __shfl_xor(accB.z, o, 64);
        accB.w += __shfl_xor(accB.w, o, 64);
    }

    if (l == 0) dsl[t >> 4] = live ? d : -1;
    if (live && l < 4) {
        float inv = 1.f / wsum;
        float4 rA, rB;
        rA.x = fmaxf(accA.x * inv + b1[4 * q4 + 0], 0.f);
        rA.y = fmaxf(accA.y * inv + b1[4 * q4 + 1], 0.f);
        rA.z = fmaxf(accA.z * inv + b1[4 * q4 + 2], 0.f);
        rA.w = fmaxf(accA.w * inv + b1[4 * q4 + 3], 0.f);
        rB.x = fmaxf(accB.x * inv + b1[16 + 4 * q4 + 0], 0.f);
        rB.y = fmaxf(accB.y * inv + b1[16 + 4 * q4 + 1], 0.f);
        rB.z = fmaxf(accB.z * inv + b1[16 + 4 * q4 + 2], 0.f);
        rB.w = fmaxf(accB.w * inv + b1[16 + 4 * q4 + 3], 0.f);
        *(float4*)&hs[t >> 4][4 * q4]      = rA;
        *(float4*)&hs[t >> 4][16 + 4 * q4] = rB;
    }
    __syncthreads();

    // ---- gemm2 epilogue (per-row 32x32 projection from LDS, planar out) ----
    int tr = t >> 4;
    int c  = t & 15;
    int r2 = dsl[tr];
    float accm = 0.f, accl = 0.f;
#pragma unroll
    for (int k = 0; k < 32; k++) {
        float hv = hs[tr][k];
        accm += hv * Wms[k][c];
        accl += hv * Wls[k][c];
    }
    if (r2 >= 0) {
        hmu[(size_t)r2 * 16 + c] = __half_as_ushort(__float2half(accm));
        hls[(size_t)r2 * 16 + c] = __half_as_ushort(__float2half(accl));
    }
    float pms = accm * amsv[c], pmd = accm * amdv[c];
    float pls = accl * alsv[c], pld = accl * aldv[c];
    for (int m = 1; m < 16; m <<= 1) {
        pms += __shfl_xor(pms, m, 64);
        pmd += __shfl_xor(pmd, m, 64);
        pls += __shfl_xor(pls, m, 64);
        pld += __shfl_xor(pld, m, 64);
    }
    if (c == 0 && r2 >= 0) {
        attn2[r2] = make_float2(pms, pls);
        amud[r2] = pmd;
        alsd[r2] = pld;
    }
}

// ---------------- layer-2 fused (two-pass planar: mu then ls) --------------
__global__ __launch_bounds__(256) void l2_fused_kernel(
    const u32* __restrict__ rowS, const u32* __restrict__ deg,
    const int* __restrict__ srcS, const u32* __restrict__ perm,
    const float2* __restrict__ attn2,
    const float* __restrict__ amud, const float* __restrict__ alsd,
    const u16* __restrict__ hmu, const u16* __restrict__ hls,
    const float* __restrict__ bm, const float* __restrict__ bl,
    float* __restrict__ out, int n, int ntot)
{
    int gid = blockIdx.x * 16 + (threadIdx.x >> 4);
    if (gid >= ntot) return;
    int d = (int)perm[gid];
    if (d >= n) return;                  // pad sentinel
    int l  = threadIdx.x & 15;
    int e4 = l >> 2;
    int q4 = l & 3;
    int gb = (threadIdx.x & 63) & 48;

    int beg = (int)rowS[d];
    int end = beg + (int)deg[d] + 1;
    int full_end = beg + ((end - beg) & ~15);
    float amdv = amud[d], aldv = alsd[d];

    float wsm = 0.f, wsl = 0.f;
    float4 accm = make_float4(0.f, 0.f, 0.f, 0.f);
    float4 accl = make_float4(0.f, 0.f, 0.f, 0.f);

    // ---- pass A: mu plane ----
    int tb = beg;
    for (; tb < full_end; tb += 16) {
        int s = srcS[tb + l];
        float pm = __expf(fminf(lrelu(attn2[s].x + amdv), 60.f));
#pragma unroll
        for (int jj = 0; jj < 16; jj += 4) {
            int idx = jj + e4;
            int sj  = __shfl(s, gb + idx, 64);
            float w = __shfl(pm, gb + idx, 64);
            wsm += w;
            float4 hv = ldq_h16(hmu + (size_t)sj * 16, q4);
            accm.x += w * hv.x; accm.y += w * hv.y;
            accm.z += w * hv.z; accm.w += w * hv.w;
        }
    }
    if (tb < end) {
        int j = tb + l;
        bool valid = j < end;
        int s = valid ? srcS[j] : 0;
        float pm = valid ? __expf(fminf(lrelu(attn2[s].x + amdv), 60.f)) : 0.f;
        int cnt = end - tb;
        for (int jj = 0; jj < cnt; jj += 4) {
            int idx = jj + e4;
            int sj  = __shfl(s, gb + idx, 64);
            float w = __shfl(pm, gb + idx, 64);
            if (idx >= cnt) w = 0.f;
            wsm += w;
            float4 hv = ldq_h16(hmu + (size_t)sj * 16, q4);
            accm.x += w * hv.x; accm.y += w * hv.y;
            accm.z += w * hv.z; accm.w += w * hv.w;
        }
    }
    // ---- pass B: ls plane ----
    tb = beg;
    for (; tb < full_end; tb += 16) {
        int s = srcS[tb + l];
        float pl = __expf(fminf(lrelu(attn2[s].y + aldv), 60.f));
#pragma unroll
        for (int jj = 0; jj < 16; jj += 4) {
            int idx = jj + e4;
            int sj  = __shfl(s, gb + idx, 64);
            float w = __shfl(pl, gb + idx, 64);
            wsl += w;
            float4 hv = ldq_h16(hls + (size_t)sj * 16, q4);
            accl.x += w * hv.x; accl.y += w * hv.y;
            accl.z += w * hv.z; accl.w += w * hv.w;
        }
    }
    if (tb < end) {
        int j = tb + l;
        bool valid = j < end;
        int s = valid ? srcS[j] : 0;
        float pl = valid ? __expf(fminf(lrelu(attn2[s].y + aldv), 60.f)) : 0.f;
        int cnt = end - tb;
        for (int jj = 0; jj < cnt; jj += 4) {
            int idx = jj + e4;
            int sj  = __shfl(s, gb + idx, 64);
            float w = __shfl(pl, gb + idx, 64);
            if (idx >= cnt) w = 0.f;
            wsl += w;
            float4 hv = ldq_h16(hls + (size_t)sj * 16, q4);
            accl.x += w * hv.x; accl.y += w * hv.y;
            accl.z += w * hv.z; accl.w += w * hv.w;
        }
    }

#pragma unroll
    for (int o = 4; o <= 8; o <<= 1) {
        wsm   += __shfl_xor(wsm, o, 64);
        wsl   += __shfl_xor(wsl, o, 64);
        accm.x += __shfl_xor(accm.x, o, 64);
        accm.y += __shfl_xor(accm.y, o, 64);
        accm.z += __shfl_xor(accm.z, o, 64);
        accm.w += __shfl_xor(accm.w, o, 64);
        accl.x += __shfl_xor(accl.x, o, 64);
        accl.y += __shfl_xor(accl.y, o, 64);
        accl.z += __shfl_xor(accl.z, o, 64);
        accl.w += __shfl_xor(accl.w, o, 64);
    }
    if (l < 4) {
        float invm = 1.f / wsm;
        float invl = 1.f / wsl;
        float4 rm, rl;
        rm.x = accm.x * invm + bm[4 * q4 + 0];
        rm.y = accm.y * invm + bm[4 * q4 + 1];
        rm.z = accm.z * invm + bm[4 * q4 + 2];
        rm.w = accm.w * invm + bm[4 * q4 + 3];
        rl.x = accl.x * invl + bl[4 * q4 + 0];
        rl.y = accl.y * invl + bl[4 * q4 + 1];
        rl.z = accl.z * invl + bl[4 * q4 + 2];
        rl.w = accl.w * invl + bl[4 * q4 + 3];
        *(float4*)&out[(size_t)d * 16 + 4 * q4] = rm;
        *(float4*)&out[(size_t)n * 16 + (size_t)d * 16 + 4 * q4] = rl;
    }
}

extern "C" void kernel_launch(void* const* d_in, const int* in_sizes, int n_in,
                              void* d_out, int out_size, void* d_ws, size_t ws_size,
                              hipStream_t stream)
{
    const float* x   = (const float*)d_in[0];
    const int*   ei  = (const int*)d_in[1];
    const float* W1  = (const float*)d_in[2];
    const float* a1s = (const float*)d_in[3];
    const float* a1d = (const float*)d_in[4];
    const float* b1  = (const float*)d_in[5];
    const float* Wm  = (const float*)d_in[6];
    const float* ams = (const float*)d_in[7];
    const float* amd = (const float*)d_in[8];
    const float* bm  = (const float*)d_in[9];
    const float* Wl  = (const float*)d_in[10];
    const float* als = (const float*)d_in[11];
    const float* ald = (const float*)d_in[12];
    const float* bl  = (const float*)d_in[13];

    int n  = in_sizes[0] / 128;
    int E  = in_sizes[1] / 2;
    int Et = E + n;
    int wsz = (n + NW - 1) / NW;          // 391 for n=100000 (fits 9 bits, <=512)
    int cap = E / NW + 3072;              // 39-sigma slack
    int ntot = NW * wsz;                  // perm index space (incl. pads)
    const int* srcI = ei;
    const int* dstI = ei + E;

    float* ws = (float*)d_ws;
    // Layout (floats):
    //  [0,8n)     hA (fp16 plane, ch 0-15) | [8n,16n) hB (ch 16-31)
    //  [16n,24n)  hmu (fp16 plane) | [24n,32n) hls
    //  [32n,64n)  pairs (u32 x NW*cap = 9.5MB)
    //  [64n,66n)  attn2 (float2) | [66n,67n) amud | [67n,68n) alsd
    //  [68n,69n)  deg | [69n,69n+NW) bcur | [70n,71n) rowS
    //  [71n,71n+Et) srcS ; [71n+Et,71n+Et+ntot) perm ; then as_/ad_
    u16*    hA   = (u16*)ws;
    u16*    hB   = (u16*)(ws + (size_t)8 * n);
    u16*    hmu  = (u16*)(ws + (size_t)16 * n);
    u16*    hls  = (u16*)(ws + (size_t)24 * n);
    u32*    pairs = (u32*)(ws + (size_t)32 * n);
    float2* attn2 = (float2*)(ws + (size_t)64 * n);
    float*  amud = ws + (size_t)66 * n;
    float*  alsd = ws + (size_t)67 * n;
    u32*    deg  = (u32*)(ws + (size_t)68 * n);
    u32*    bcur = (u32*)(ws + (size_t)69 * n);
    u32*    rowS = (u32*)(ws + (size_t)70 * n);
    int*    srcS = (int*)(ws + (size_t)71 * n);
    u32*    perm = (u32*)(ws + (size_t)71 * n + Et);
    float*  as_  = ws + (size_t)71 * n + Et + ntot;
    float*  ad_  = as_ + n;

    int pgrid = (E + PCHUNK - 1) / PCHUNK;
    int gblocks = (n + 63) / 64;

    hipMemsetAsync(bcur, 0, NW * sizeof(u32), stream);

    partition_kernel<<<pgrid, 256, 0, stream>>>(srcI, dstI, pairs, bcur,
                                                E, wsz, cap);

    g1c_kernel<<<NW + gblocks, 256, 0, stream>>>(
        x, W1, a1s, a1d, hA, hB, as_, ad_,
        pairs, bcur, rowS, deg, srcS, perm, n, wsz, cap);

    l1g2_kernel<<<(ntot + 15) / 16, 256, 0, stream>>>(
        rowS, deg, srcS, perm, as_, ad_, hA, hB, b1,
        Wm, Wl, ams, amd, als, ald,
        hmu, hls, attn2, amud, alsd, n, ntot);

    l2_fused_kernel<<<(ntot + 15) / 16, 256, 0, stream>>>(rowS, deg, srcS, perm,
                                                          attn2, amud, alsd,
                                                          hmu, hls, bm, bl,
                                                          (float*)d_out, n, ntot);
}

// Round 16
// 228.465 us; speedup vs baseline: 1.1568x; 1.1568x over previous
//
#include <hip/hip_runtime.h>
#include <hip/hip_bf16.h>
#include <hip/hip_fp16.h>

typedef unsigned int u32;
typedef unsigned short u16;

__device__ __forceinline__ float lrelu(float v) {
    return v > 0.f ? v : 0.2f * v;
}

// load quad q (4 halves = 8B) of a 32-half row, convert to float4
__device__ __forceinline__ float4 ldq_h16(const u16* __restrict__ row, int q) {
    uint2 u = ((const uint2*)row)[q];
    __half2 a = *(__half2*)&u.x;
    __half2 b = *(__half2*)&u.y;
    float2 fa = __half22float2(a);
    float2 fb = __half22float2(b);
    return make_float4(fa.x, fa.y, fb.x, fb.y);
}

__device__ __forceinline__ u32 pack2h(float x, float y) {
    __half2 h = __float22half2_rn(make_float2(x, y));
    return *(u32*)&h;
}

#define PCHUNK 4096
#define NW 256

// ---------------- partition (standalone, full occupancy) -------------------
// 2KB LDS -> 8 blk/CU; int4-vectorized edge loads.
__global__ __launch_bounds__(256) void partition_kernel(
    const int* __restrict__ srcI, const int* __restrict__ dstI,
    u32* __restrict__ pairs, u32* __restrict__ bcur,
    int E, int wsz, int cap)
{
    __shared__ u32 lcount[NW];
    __shared__ u32 lbase[NW];
    int t = threadIdx.x;
    int chunk = blockIdx.x * PCHUNK;
    lcount[t] = 0;
    __syncthreads();
    u32 pk[16]; int wv[16]; u32 rk[16]; bool val[16];
#pragma unroll
    for (int g = 0; g < 4; g++) {
        int i0 = chunk + g * 1024 + 4 * t;
        int4 s4, d4;
        bool v4 = (i0 + 3) < E;
        if (v4) {
            s4 = *(const int4*)&srcI[i0];
            d4 = *(const int4*)&dstI[i0];
        }
        int sv[4] = {s4.x, s4.y, s4.z, s4.w};
        int dv[4] = {d4.x, d4.y, d4.z, d4.w};
#pragma unroll
        for (int j = 0; j < 4; j++) {
            int k = g * 4 + j;
            int i = i0 + j;
            val[k] = i < E;
            if (val[k]) {
                u32 s, d;
                if (v4) { s = (u32)sv[j]; d = (u32)dv[j]; }
                else    { s = (u32)srcI[i]; d = (u32)dstI[i]; }
                wv[k] = d / (u32)wsz;
                u32 dloc = d - (u32)wv[k] * (u32)wsz;
                pk[k] = (dloc << 17) | s;
                rk[k] = atomicAdd(&lcount[wv[k]], 1u);
            }
        }
    }
    __syncthreads();
    if (lcount[t] > 0)
        lbase[t] = atomicAdd(&bcur[t], lcount[t]);
    __syncthreads();
#pragma unroll
    for (int k = 0; k < 16; k++) {
        if (val[k]) {
            u32 pos = lbase[wv[k]] + rk[k];
            if (pos < (u32)cap)   // overflow guard (P ~ 0, 39 sigma)
                pairs[(size_t)wv[k] * cap + pos] = pk[k];
        }
    }
}

// Shared-memory overlays for the csr ∥ gemm1 fat kernel.
struct GSm { float xs[64][132]; float Wl[128][32]; float asv[32], adv[32]; };
struct CSm { u32 dw[512], cw[512], ts[256], hb[512]; };

// ---------------- FAT: csr (blocks [0,NW)) ∥ gemm1 (rest) ------------------
__global__ __launch_bounds__(256) void g1c_kernel(
    const float* __restrict__ x, const float* __restrict__ W,
    const float* __restrict__ a_src, const float* __restrict__ a_dst,
    u16* __restrict__ h16, float* __restrict__ as_, float* __restrict__ ad_,
    const u32* __restrict__ pairs, const u32* __restrict__ bcur,
    u32* __restrict__ rowS, u32* __restrict__ deg, int* __restrict__ srcS,
    u32* __restrict__ perm,
    int n, int wsz, int cap)
{
    __shared__ __align__(16) char smraw[sizeof(GSm)];
    int t = threadIdx.x;

    if ((int)blockIdx.x < NW) {
        // ---- csr body (R12-verbatim, arrays via overlay) ----
        CSm& s = *reinterpret_cast<CSm*>(smraw);
        int grp = blockIdx.x;
        int wlo = grp * wsz;
        int wnodes = n - wlo; if (wnodes < 0) wnodes = 0; if (wnodes > wsz) wnodes = wsz;
        u32 cnt = bcur[grp]; if (cnt > (u32)cap) cnt = (u32)cap;
        size_t base = (size_t)grp * cap;

        {
            int wlo_t = t * wsz;
            int wn_t = n - wlo_t; if (wn_t < 0) wn_t = 0; if (wn_t > wsz) wn_t = wsz;
            u32 c_t = bcur[t]; if (c_t > (u32)cap) c_t = (u32)cap;
            s.ts[t] = c_t + (u32)wn_t;
            __syncthreads();
            for (int o = 1; o < NW; o <<= 1) {
                u32 y = (t >= o) ? s.ts[t - o] : 0u;
                __syncthreads();
                s.ts[t] += y;
                __syncthreads();
            }
        }
        u32 wb = s.ts[grp] - (cnt + (u32)wnodes);
        __syncthreads();

        s.dw[t] = 0; s.dw[t + 256] = 0;
        s.hb[t] = 0; s.hb[t + 256] = 0;
        __syncthreads();
        for (u32 i = t; i < cnt; i += 256)
            atomicAdd(&s.dw[pairs[base + i] >> 17], 1u);
        __syncthreads();

        int i0 = 2 * t, i1 = 2 * t + 1;
        u32 e0 = (i0 < wnodes) ? s.dw[i0] + 1u : 0u;
        u32 e1 = (i1 < wnodes) ? s.dw[i1] + 1u : 0u;
        s.ts[t] = e0 + e1;
        __syncthreads();
        for (int o = 1; o < 256; o <<= 1) {
            u32 y = (t >= o) ? s.ts[t - o] : 0u;
            __syncthreads();
            s.ts[t] += y;
            __syncthreads();
        }
        u32 off = wb + s.ts[t] - (e0 + e1);
        if (i0 < wnodes) {
            u32 dgi = s.dw[i0];
            s.cw[i0] = off;
            rowS[wlo + i0] = off;
            deg[wlo + i0] = dgi;
            srcS[off + dgi] = wlo + i0;      // self-loop at last slot
        }
        u32 off1 = off + e0;
        if (i1 < wnodes) {
            u32 dgi = s.dw[i1];
            s.cw[i1] = off1;
            rowS[wlo + i1] = off1;
            deg[wlo + i1] = dgi;
            srcS[off1 + dgi] = wlo + i1;
        }
        __syncthreads();

        // degree counting-sort -> perm (ascending degree within window)
        for (int i = t; i < wnodes; i += 256)
            atomicAdd(&s.hb[s.dw[i] < 511u ? s.dw[i] : 511u], 1u);
        __syncthreads();
        {
            u32 h0 = s.hb[2 * t], h1 = s.hb[2 * t + 1];
            s.ts[t] = h0 + h1;
            __syncthreads();
            for (int o = 1; o < 256; o <<= 1) {
                u32 y = (t >= o) ? s.ts[t - o] : 0u;
                __syncthreads();
                s.ts[t] += y;
                __syncthreads();
            }
            u32 b0 = s.ts[t] - (h0 + h1);
            s.hb[2 * t] = b0;
            s.hb[2 * t + 1] = b0 + h0;
        }
        __syncthreads();
        for (int i = t; i < wnodes; i += 256) {
            u32 dg = s.dw[i] < 511u ? s.dw[i] : 511u;
            u32 pos = atomicAdd(&s.hb[dg], 1u);
            perm[wlo + pos] = (u32)(wlo + i);
        }
        for (int i = wnodes + t; i < wsz; i += 256)
            perm[wlo + i] = 0x7fffffffu;      // pad sentinel
        __syncthreads();

        // scatter (slab L2-hot from hist pass)
        for (u32 i = t; i < cnt; i += 256) {
            u32 pr = pairs[base + i];
            u32 pos = atomicAdd(&s.cw[pr >> 17], 1u);
            srcS[pos] = (int)(pr & 0x1FFFFu);
        }
        return;
    }

    // ---- gemm1 body (R8/R12-exact): h16 = fp16(x @ W1) + as_/ad_ dots ----
    GSm& s = *reinterpret_cast<GSm*>(smraw);
    int rb = (blockIdx.x - NW) * 64;

    for (int i = t; i < 4096; i += 256) s.Wl[i >> 5][i & 31] = W[i];
    if (t < 32) { s.asv[t] = a_src[t]; s.adv[t] = a_dst[t]; }
    for (int i = t; i < 2048; i += 256) {
        int row = i >> 5, seg = i & 31;
        float4 v = make_float4(0.f, 0.f, 0.f, 0.f);
        if (rb + row < n)
            v = ((const float4*)(x + (size_t)(rb + row) * 128))[seg];
        int c = seg * 4;
        s.xs[row][c + 0] = v.x; s.xs[row][c + 1] = v.y;
        s.xs[row][c + 2] = v.z; s.xs[row][c + 3] = v.w;
    }
    __syncthreads();

    int tr = t >> 3;
    int tc = t & 7;
    float acc[2][4];
#pragma unroll
    for (int i = 0; i < 2; i++)
#pragma unroll
        for (int j = 0; j < 4; j++) acc[i][j] = 0.f;

#pragma unroll 4
    for (int k = 0; k < 128; k++) {
        float x0 = s.xs[tr][k];
        float x1 = s.xs[tr + 32][k];
        float4 wv = *(const float4*)&s.Wl[k][tc * 4];
        acc[0][0] += x0 * wv.x; acc[0][1] += x0 * wv.y;
        acc[0][2] += x0 * wv.z; acc[0][3] += x0 * wv.w;
        acc[1][0] += x1 * wv.x; acc[1][1] += x1 * wv.y;
        acc[1][2] += x1 * wv.z; acc[1][3] += x1 * wv.w;
    }

#pragma unroll
    for (int i = 0; i < 2; i++) {
        int r = rb + tr + i * 32;
        if (r < n) {
            uint2 p;
            p.x = pack2h(acc[i][0], acc[i][1]);
            p.y = pack2h(acc[i][2], acc[i][3]);
            *(uint2*)&h16[(size_t)r * 32 + tc * 4] = p;
        }
        float ps = 0.f, pd = 0.f;
#pragma unroll
        for (int j = 0; j < 4; j++) {
            int c = tc * 4 + j;
            ps += acc[i][j] * s.asv[c];
            pd += acc[i][j] * s.adv[c];
        }
        for (int m = 1; m < 8; m <<= 1) {
            ps += __shfl_xor(ps, m, 64);
            pd += __shfl_xor(pd, m, 64);
        }
        if (tc == 0 && r < n) { as_[r] = ps; ad_[r] = pd; }
    }
}

// ------------ layer-1 + GEMM2 fused (quarter-wave, degree-sorted) ---------
// ALL tiles run the fully-unrolled 8-iteration inner body with a per-iter
// predication kill (idx >= cnt -> w = 0): full tiles pay 8 cheap cndmasks,
// tail tiles gain 8-deep gather MLP (R14 left the tail on a 2-chain path).
// Killed slots gather row 0 (L1-hot broadcast) — R3-verified semantics.
// NO EARLY RETURNS (barriers).
__global__ __launch_bounds__(256) void l1g2_kernel(
    const u32* __restrict__ rowS, const u32* __restrict__ deg,
    const int* __restrict__ srcS, const u32* __restrict__ perm,
    const float* __restrict__ as_, const float* __restrict__ ad_,
    const u16* __restrict__ h16, const float* __restrict__ b1,
    const float* __restrict__ Wm, const float* __restrict__ Wl_,
    const float* __restrict__ ams, const float* __restrict__ amd,
    const float* __restrict__ alsb, const float* __restrict__ ald,
    u16* __restrict__ hmhl16, float2* __restrict__ attn2,
    float* __restrict__ amud, float* __restrict__ alsd,
    int n, int ntot)
{
    __shared__ float hs[16][36];
    __shared__ float Wms[32][16], Wls[32][16];
    __shared__ float amsv[16], amdv[16], alsv[16], aldv[16];
    __shared__ int dsl[16];
    int t = threadIdx.x;

    for (int i = t; i < 512; i += 256) {
        Wms[i >> 4][i & 15] = Wm[i];
        Wls[i >> 4][i & 15] = Wl_[i];
    }
    if (t < 16) {
        amsv[t] = ams[t]; amdv[t] = amd[t];
        alsv[t] = alsb[t]; aldv[t] = ald[t];
    }

    int gid = blockIdx.x * 16 + (t >> 4);
    int d = (gid < ntot) ? (int)perm[gid] : 0x7fffffff;
    bool live = (u32)d < (u32)n;
    int l  = t & 15;           // lane in group
    int e2 = l >> 3;           // edge parity
    int q  = l & 7;            // quad of the 32-ch row
    int gb = (t & 63) & 48;    // group base lane within wave

    int beg = 0, end = 0;
    float adv = 0.f;
    if (live) {
        beg = (int)rowS[d];
        end = beg + (int)deg[d] + 1;
        adv = ad_[d];
    }

    float wsum = 0.f;
    float4 acc = make_float4(0.f, 0.f, 0.f, 0.f);

    for (int tb = beg; tb < end; tb += 16) {
        int j = tb + l;
        bool valid = j < end;
        int s = valid ? srcS[j] : 0;
        float p = valid ? __expf(fminf(lrelu(as_[s] + adv), 60.f)) : 0.f;
        int cnt = end - tb; if (cnt > 16) cnt = 16;
#pragma unroll
        for (int jj = 0; jj < 16; jj += 2) {
            int idx = jj + e2;
            int sj  = __shfl(s, gb + idx, 64);
            float w = __shfl(p, gb + idx, 64);
            if (idx >= cnt) w = 0.f;     // convergent kill (row 0 broadcast)
            wsum += w;
            float4 hv = ldq_h16(h16 + (size_t)sj * 32, q);
            acc.x += w * hv.x; acc.y += w * hv.y;
            acc.z += w * hv.z; acc.w += w * hv.w;
        }
    }
    wsum  += __shfl_xor(wsum, 8, 64);
    acc.x += __shfl_xor(acc.x, 8, 64);
    acc.y += __shfl_xor(acc.y, 8, 64);
    acc.z += __shfl_xor(acc.z, 8, 64);
    acc.w += __shfl_xor(acc.w, 8, 64);

    if (l == 0) dsl[t >> 4] = live ? d : -1;
    if (live && l < 8) {
        float inv = 1.f / wsum;
        float4 r;
        r.x = fmaxf(acc.x * inv + b1[4 * q + 0], 0.f);
        r.y = fmaxf(acc.y * inv + b1[4 * q + 1], 0.f);
        r.z = fmaxf(acc.z * inv + b1[4 * q + 2], 0.f);
        r.w = fmaxf(acc.w * inv + b1[4 * q + 3], 0.f);
        *(float4*)&hs[t >> 4][4 * q] = r;
    }
    __syncthreads();

    // ---- gemm2 epilogue (per-row 32x32 projection from LDS) ----
    int tr = t >> 4;
    int c  = t & 15;
    int r2 = dsl[tr];
    float accm = 0.f, accl = 0.f;
#pragma unroll
    for (int k = 0; k < 32; k++) {
        float hv = hs[tr][k];
        accm += hv * Wms[k][c];
        accl += hv * Wls[k][c];
    }
    if (r2 >= 0) {
        hmhl16[(size_t)r2 * 32 + c]      = __half_as_ushort(__float2half(accm));
        hmhl16[(size_t)r2 * 32 + 16 + c] = __half_as_ushort(__float2half(accl));
    }
    float pms = accm * amsv[c], pmd = accm * amdv[c];
    float pls = accl * alsv[c], pld = accl * aldv[c];
    for (int m = 1; m < 16; m <<= 1) {
        pms += __shfl_xor(pms, m, 64);
        pmd += __shfl_xor(pmd, m, 64);
        pls += __shfl_xor(pls, m, 64);
        pld += __shfl_xor(pld, m, 64);
    }
    if (c == 0 && r2 >= 0) {
        attn2[r2] = make_float2(pms, pls);
        amud[r2] = pmd;
        alsd[r2] = pld;
    }
}

// ---------------- layer-2 fused (quarter-wave, degree-sorted perm) ---------
// Same single-path fully-unrolled body with predication kill.
__global__ __launch_bounds__(256) void l2_fused_kernel(
    const u32* __restrict__ rowS, const u32* __restrict__ deg,
    const int* __restrict__ srcS, const u32* __restrict__ perm,
    const float2* __restrict__ attn2,
    const float* __restrict__ amud, const float* __restrict__ alsd,
    const u16* __restrict__ hmhl16,
    const float* __restrict__ bm, const float* __restrict__ bl,
    float* __restrict__ out, int n, int ntot)
{
    int gid = blockIdx.x * 16 + (threadIdx.x >> 4);
    if (gid >= ntot) return;
    int d = (int)perm[gid];
    if (d >= n) return;                  // pad sentinel
    int l  = threadIdx.x & 15;
    int e2 = l >> 3;
    int q  = l & 7;
    int gb = (threadIdx.x & 63) & 48;
    bool isMu = q < 4;

    int beg = (int)rowS[d];
    int end = beg + (int)deg[d] + 1;
    float amdv = amud[d], aldv = alsd[d];

    float wsum = 0.f;
    float4 acc = make_float4(0.f, 0.f, 0.f, 0.f);

    for (int tb = beg; tb < end; tb += 16) {
        int j = tb + l;
        bool valid = j < end;
        int s = valid ? srcS[j] : 0;
        float2 a2 = valid ? attn2[s] : make_float2(0.f, 0.f);
        float pm = valid ? __expf(fminf(lrelu(a2.x + amdv), 60.f)) : 0.f;
        float pl = valid ? __expf(fminf(lrelu(a2.y + aldv), 60.f)) : 0.f;
        int cnt = end - tb; if (cnt > 16) cnt = 16;
#pragma unroll
        for (int jj = 0; jj < 16; jj += 2) {
            int idx = jj + e2;
            int sj    = __shfl(s, gb + idx, 64);
            float pmj = __shfl(pm, gb + idx, 64);
            float plj = __shfl(pl, gb + idx, 64);
            float w = isMu ? pmj : plj;
            if (idx >= cnt) w = 0.f;
            wsum += w;
            float4 hv = ldq_h16(hmhl16 + (size_t)sj * 32, q);
            acc.x += w * hv.x; acc.y += w * hv.y;
            acc.z += w * hv.z; acc.w += w * hv.w;
        }
    }
    wsum  += __shfl_xor(wsum, 8, 64);    // same q, other parity
    acc.x += __shfl_xor(acc.x, 8, 64);
    acc.y += __shfl_xor(acc.y, 8, 64);
    acc.z += __shfl_xor(acc.z, 8, 64);
    acc.w += __shfl_xor(acc.w, 8, 64);
    if (l < 8) {
        float inv = 1.f / wsum;          // s_m for q<4, s_l for q>=4
        if (q < 4) {
            float4 r;
            r.x = acc.x * inv + bm[4 * q + 0];
            r.y = acc.y * inv + bm[4 * q + 1];
            r.z = acc.z * inv + bm[4 * q + 2];
            r.w = acc.w * inv + bm[4 * q + 3];
            *(float4*)&out[(size_t)d * 16 + 4 * q] = r;
        } else {
            int qc = 4 * (q - 4);
            float4 r;
            r.x = acc.x * inv + bl[qc + 0];
            r.y = acc.y * inv + bl[qc + 1];
            r.z = acc.z * inv + bl[qc + 2];
            r.w = acc.w * inv + bl[qc + 3];
            *(float4*)&out[(size_t)n * 16 + (size_t)d * 16 + qc] = r;
        }
    }
}

extern "C" void kernel_launch(void* const* d_in, const int* in_sizes, int n_in,
                              void* d_out, int out_size, void* d_ws, size_t ws_size,
                              hipStream_t stream)
{
    const float* x   = (const float*)d_in[0];
    const int*   ei  = (const int*)d_in[1];
    const float* W1  = (const float*)d_in[2];
    const float* a1s = (const float*)d_in[3];
    const float* a1d = (const float*)d_in[4];
    const float* b1  = (const float*)d_in[5];
    const float* Wm  = (const float*)d_in[6];
    const float* ams = (const float*)d_in[7];
    const float* amd = (const float*)d_in[8];
    const float* bm  = (const float*)d_in[9];
    const float* Wl  = (const float*)d_in[10];
    const float* als = (const float*)d_in[11];
    const float* ald = (const float*)d_in[12];
    const float* bl  = (const float*)d_in[13];

    int n  = in_sizes[0] / 128;
    int E  = in_sizes[1] / 2;
    int Et = E + n;
    int wsz = (n + NW - 1) / NW;          // 391 for n=100000 (fits 9 bits, <=512)
    int cap = E / NW + 3072;              // 39-sigma slack
    int ntot = NW * wsz;                  // perm index space (incl. pads)
    const int* srcI = ei;
    const int* dstI = ei + E;

    float* ws = (float*)d_ws;
    // Layout (floats):
    //  [0,16n)    h16 (fp16) | [16n,32n) hmhl16 (fp16, [mu16|ls16])
    //  [32n,64n)  pairs (u32 x NW*cap = 9.5MB)
    //  [64n,66n)  attn2 (float2) | [66n,67n) amud | [67n,68n) alsd
    //  [68n,69n)  deg | [69n,69n+NW) bcur | [70n,71n) rowS
    //  [71n,71n+Et) srcS ; [71n+Et,71n+Et+ntot) perm ; then as_/ad_
    u16*    h16   = (u16*)ws;
    u16*    hmhl16 = (u16*)(ws + (size_t)16 * n);
    u32*    pairs = (u32*)(ws + (size_t)32 * n);
    float2* attn2 = (float2*)(ws + (size_t)64 * n);
    float*  amud = ws + (size_t)66 * n;
    float*  alsd = ws + (size_t)67 * n;
    u32*    deg  = (u32*)(ws + (size_t)68 * n);
    u32*    bcur = (u32*)(ws + (size_t)69 * n);
    u32*    rowS = (u32*)(ws + (size_t)70 * n);
    int*    srcS = (int*)(ws + (size_t)71 * n);
    u32*    perm = (u32*)(ws + (size_t)71 * n + Et);
    float*  as_  = ws + (size_t)71 * n + Et + ntot;
    float*  ad_  = as_ + n;

    int pgrid = (E + PCHUNK - 1) / PCHUNK;
    int gblocks = (n + 63) / 64;

    hipMemsetAsync(bcur, 0, NW * sizeof(u32), stream);

    partition_kernel<<<pgrid, 256, 0, stream>>>(srcI, dstI, pairs, bcur,
                                                E, wsz, cap);

    g1c_kernel<<<NW + gblocks, 256, 0, stream>>>(
        x, W1, a1s, a1d, h16, as_, ad_,
        pairs, bcur, rowS, deg, srcS, perm, n, wsz, cap);

    l1g2_kernel<<<(ntot + 15) / 16, 256, 0, stream>>>(
        rowS, deg, srcS, perm, as_, ad_, h16, b1,
        Wm, Wl, ams, amd, als, ald,
        hmhl16, attn2, amud, alsd, n, ntot);

    l2_fused_kernel<<<(ntot + 15) / 16, 256, 0, stream>>>(rowS, deg, srcS, perm,
                                                          attn2, amud, alsd,
                                                          hmhl16, bm, bl,
                                                          (float*)d_out, n, ntot);
}